// Round 1
// baseline (76.136 us; speedup 1.0000x reference)
//
#include <hip/hip_runtime.h>
#include <hip/hip_bf16.h>

typedef __attribute__((ext_vector_type(8))) short bf16x8;
typedef __attribute__((ext_vector_type(4))) float f32x4;

#define NPOS 147456      // 384*384
#define NTILES 9216      // NPOS/16
#define TPW 2            // tiles per wave
#define WPB 4            // waves per block
#define NBLK (NTILES / (TPW * WPB))   // 1152

__device__ inline short bfc(float f) {
  union { __hip_bfloat16 h; short s; } u;
  u.h = __float2bfloat16(f);
  return u.s;
}

__global__ __launch_bounds__(256, 2) void tpa_kernel(
    const float* __restrict__ qe, const float* __restrict__ tpr,
    const float* __restrict__ tmk_p, const float* __restrict__ wq,
    const float* __restrict__ wk, const float* __restrict__ wv,
    const float* __restrict__ wo, const float* __restrict__ ob,
    float* __restrict__ out)
{
  __shared__ unsigned short wqT[8192];        // [col=h*16+d][k=c(128)] bf16, swizzled
  __shared__ unsigned short woT[8192];        // [col=cq(128)][k=h*16+d(64)] bf16, swizzled
  __shared__ unsigned short wvbuf[WPB][1024]; // per-wave [pos(16)][hd(64)] bf16, swizzled

  const int tid   = threadIdx.x;
  const int wid   = tid >> 6;
  const int lane  = tid & 63;
  const int row16 = lane & 15;
  const int grp   = lane >> 4;

  // ---- stage Wq^T (pre-scaled by D^-0.5) and Wo^T into LDS ----
  for (int e = tid; e < 8192; e += 256) {
    { // wq: [h][c][d]
      int h = e >> 11, c = (e >> 4) & 127, d = e & 15;
      int col = h * 16 + d;
      wqT[(col * 128 + c) ^ ((col & 7) << 3)] = (unsigned short)bfc(wq[e] * 0.25f);
    }
    { // wo: [h][d][cq]
      int h = e >> 11, d = (e >> 7) & 15, cq = e & 127;
      int k = h * 16 + d;
      woT[(cq * 64 + k) ^ ((cq & 7) << 3)] = (unsigned short)bfc(wo[e]);
    }
  }

  // ---- per-lane Wk/Wv fragments (used as MFMA A-operand, swapped GEMM) ----
  bf16x8 bk[4][2], bv[4][2];
  #pragma unroll
  for (int n = 0; n < 4; ++n)
    #pragma unroll
    for (int kc = 0; kc < 2; ++kc)
      #pragma unroll
      for (int e = 0; e < 8; ++e) {
        int c = kc * 32 + grp * 8 + e;
        bk[n][kc][e] = bfc(wk[n * 1024 + c * 16 + row16]);
        bv[n][kc][e] = bfc(wv[n * 1024 + c * 16 + row16]);
      }

  const float m0 = tmk_p[0], m1 = tmk_p[1], m2 = tmk_p[2], m3 = tmk_p[3];
  const float biasv[4] = {65504.0f * (m0 - 1.0f), 65504.0f * (m1 - 1.0f),
                          65504.0f * (m2 - 1.0f), 65504.0f * (m3 - 1.0f)};
  const float tmk = (m0 + m1 + m2 + m3 > 0.0f) ? 1.0f : 0.0f;

  float obr[8];
  #pragma unroll
  for (int n8 = 0; n8 < 8; ++n8) obr[n8] = ob[n8 * 16 + row16] * tmk;

  __syncthreads();

  const int gwave = blockIdx.x * WPB + wid;

  for (int it = 0; it < TPW; ++it) {
    const int p0 = (gwave * TPW + it) * 16;

    // ---- issue ALL global loads for this tile first (MLP) ----
    f32x4 qv[8];
    {
      const f32x4* qbase = reinterpret_cast<const f32x4*>(qe) + (p0 + row16) * 32 + grp * 2;
      #pragma unroll
      for (int kc = 0; kc < 4; ++kc) {
        qv[kc * 2 + 0] = qbase[kc * 8 + 0];
        qv[kc * 2 + 1] = qbase[kc * 8 + 1];
      }
    }
    f32x4 tv[4][4];
    #pragma unroll
    for (int t = 0; t < 4; ++t) {
      const f32x4* tbase = reinterpret_cast<const f32x4*>(tpr) + (t * NPOS + p0 + row16) * 16 + grp * 2;
      #pragma unroll
      for (int kc = 0; kc < 2; ++kc) {
        tv[t][kc * 2 + 0] = tbase[kc * 8 + 0];
        tv[t][kc * 2 + 1] = tbase[kc * 8 + 1];
      }
    }

    // ---- GEMM1 (swapped): qT[n] holds Q^T tile, lane = [d=grp*4+r][pos=row16] ----
    bf16x8 aq[4];
    #pragma unroll
    for (int kc = 0; kc < 4; ++kc)
      #pragma unroll
      for (int e = 0; e < 8; ++e)
        aq[kc][e] = bfc(e < 4 ? qv[kc * 2 + 0][e] : qv[kc * 2 + 1][e - 4]);

    f32x4 qT[4];
    #pragma unroll
    for (int n = 0; n < 4; ++n) {
      qT[n] = (f32x4){0.f, 0.f, 0.f, 0.f};
      #pragma unroll
      for (int kc = 0; kc < 4; ++kc) {
        const bf16x8 a = *reinterpret_cast<const bf16x8*>(
            &wqT[(((n * 16 + row16) * 128) + kc * 32 + grp * 8) ^ ((row16 & 7) << 3)]);
        qT[n] = __builtin_amdgcn_mfma_f32_16x16x32_bf16(a, aq[kc], qT[n], 0, 0, 0);
      }
    }

    // ---- template loop: K/V proj + online (no-max) softmax accumulate ----
    float ssum[4] = {0.f, 0.f, 0.f, 0.f};
    f32x4 wvT[4];
    #pragma unroll
    for (int n = 0; n < 4; ++n) wvT[n] = (f32x4){0.f, 0.f, 0.f, 0.f};

    #pragma unroll
    for (int t = 0; t < 4; ++t) {
      bf16x8 at[2];
      #pragma unroll
      for (int kc = 0; kc < 2; ++kc)
        #pragma unroll
        for (int e = 0; e < 8; ++e)
          at[kc][e] = bfc(e < 4 ? tv[t][kc * 2 + 0][e] : tv[t][kc * 2 + 1][e - 4]);

      f32x4 kT[4], vT[4];
      #pragma unroll
      for (int n = 0; n < 4; ++n) {
        kT[n] = (f32x4){0.f, 0.f, 0.f, 0.f};
        vT[n] = (f32x4){0.f, 0.f, 0.f, 0.f};
        #pragma unroll
        for (int kc = 0; kc < 2; ++kc) {
          kT[n] = __builtin_amdgcn_mfma_f32_16x16x32_bf16(bk[n][kc], at[kc], kT[n], 0, 0, 0);
          vT[n] = __builtin_amdgcn_mfma_f32_16x16x32_bf16(bv[n][kc], at[kc], vT[n], 0, 0, 0);
        }
      }
      #pragma unroll
      for (int n = 0; n < 4; ++n) {
        float lg = qT[n][0] * kT[n][0] + qT[n][1] * kT[n][1] +
                   qT[n][2] * kT[n][2] + qT[n][3] * kT[n][3];
        lg += __shfl_xor(lg, 16);
        lg += __shfl_xor(lg, 32);          // logit for (pos=row16, head n), bcast to all grps
        const float w = __expf(lg + biasv[t]);
        ssum[n] += w;
        #pragma unroll
        for (int r = 0; r < 4; ++r) wvT[n][r] += w * vT[n][r];
      }
    }

    // ---- normalize, transpose WV via per-wave LDS ----
    #pragma unroll
    for (int n = 0; n < 4; ++n) {
      const float inv = tmk / fmaxf(ssum[n], 1e-30f);
      #pragma unroll
      for (int r = 0; r < 4; ++r) {
        const int hd = n * 16 + grp * 4 + r;
        wvbuf[wid][(row16 * 64 + hd) ^ ((row16 & 7) << 3)] =
            (unsigned short)bfc(wvT[n][r] * inv);
      }
    }
    asm volatile("s_waitcnt lgkmcnt(0)" ::: "memory");
    __builtin_amdgcn_sched_barrier(0);

    bf16x8 awv[2];
    #pragma unroll
    for (int kc = 0; kc < 2; ++kc)
      awv[kc] = *reinterpret_cast<const bf16x8*>(
          &wvbuf[wid][(row16 * 64 + kc * 32 + grp * 8) ^ ((row16 & 7) << 3)]);

    // ---- GEMM4 + epilogue store ----
    const int orow0 = p0 + grp * 4;
    #pragma unroll
    for (int n8 = 0; n8 < 8; ++n8) {
      f32x4 acc = (f32x4){0.f, 0.f, 0.f, 0.f};
      #pragma unroll
      for (int kc = 0; kc < 2; ++kc) {
        const bf16x8 b = *reinterpret_cast<const bf16x8*>(
            &woT[(((n8 * 16 + row16) * 64) + kc * 32 + grp * 8) ^ ((row16 & 7) << 3)]);
        acc = __builtin_amdgcn_mfma_f32_16x16x32_bf16(awv[kc], b, acc, 0, 0, 0);
      }
      #pragma unroll
      for (int r = 0; r < 4; ++r)
        out[(orow0 + r) * 128 + n8 * 16 + row16] = acc[r] + obr[n8];
    }
  }
}

extern "C" void kernel_launch(void* const* d_in, const int* in_sizes, int n_in,
                              void* d_out, int out_size, void* d_ws, size_t ws_size,
                              hipStream_t stream) {
  const float* qe  = (const float*)d_in[0];
  const float* tpr = (const float*)d_in[1];
  const float* tmk = (const float*)d_in[2];
  const float* wq  = (const float*)d_in[3];
  const float* wk  = (const float*)d_in[4];
  const float* wv  = (const float*)d_in[5];
  const float* wo  = (const float*)d_in[6];
  const float* ob  = (const float*)d_in[7];
  float* out = (float*)d_out;

  tpa_kernel<<<NBLK, 256, 0, stream>>>(qe, tpr, tmk, wq, wk, wv, wo, ob, out);
}